// Round 6
// baseline (256.446 us; speedup 1.0000x reference)
//
#include <hip/hip_runtime.h>

#define BB   4
#define NN   256
#define TT   4096
#define DD   128      // SIM_DIM
#define LK   101      // LOOKUP
#define PADK 50
#define OD   128      // OUT_DIM
#define ROWS 164      // 64 + LK - 1 rows of halo'd proj window
#define RSTR 33       // band: row stride in float4 units (132 floats, +4 pad)
#define FSTR 260      // proj fs row stride floats (1040 B: 16B-aligned, 8-group bank spread)
#define CPB  8        // pool chunks per block

typedef float vfloat4 __attribute__((ext_vector_type(4)));

// -------- kernel 1: spatial mean-pool (HBM-bound) + folded weight transpose --------
// 8192 blocks x 256 thr, 8 blocks/CU (max TLP; latency hidden by waves, no pipelining).
// Blocks 0..63 additionally transpose w_proj/w_fc (runs inside this kernel's window).
__global__ __launch_bounds__(256, 8) void pool_kernel(
    const float* __restrict__ x, float* __restrict__ feat,
    const float* __restrict__ w_proj, const float* __restrict__ w_fc,
    float* __restrict__ w_t, float* __restrict__ wfc_t) {
  __shared__ float part[2][768];
  int tid = threadIdx.x;
  for (int c = 0; c < CPB; ++c) {
    size_t ck = (size_t)blockIdx.x * CPB + c;
    const vfloat4* x4 = (const vfloat4*)(x + ck * 3072);
    float* pb = part[c & 1];
#pragma unroll
    for (int p = 0; p < 3; ++p) {
      vfloat4 v = __builtin_nontemporal_load(&x4[p * 256 + tid]);
      pb[p * 256 + tid] = (v.x + v.y) + (v.z + v.w);
    }
    __syncthreads();
    if (tid < 64) {
      float s0 = 0.f, s1 = 0.f;
      const float* pp = pb + tid * 12;
#pragma unroll
      for (int i = 0; i < 6; ++i) { s0 += pp[i]; s1 += pp[6 + i]; }
      feat[ck * 64 + tid] = (s0 + s1) * (1.0f / 48.0f);
    }
  }
  // folded transposes (blocks 0..63): w_proj[128][256] -> w_t[256][128];
  // w_fc[128][101] -> wfc_t[101][128]
  if (blockIdx.x < 64) {
    int idx = blockIdx.x * 256 + tid;          // 0..16383
#pragma unroll
    for (int r = 0; r < 2; ++r) {
      int i = idx + r * 16384;                 // covers 32768 = DD*NN
      int d = i >> 8, n = i & 255;
      w_t[n * DD + d] = w_proj[i];
    }
    if (idx < OD * LK) {
      int o = idx / LK, j = idx - o * LK;
      wfc_t[j * OD + o] = w_fc[idx];
    }
  }
}

// ---------------- kernel 2: projection + L2 normalize ----------------
// 512 blocks (b, 32-t tile) x 512 thr, 34.4 KB LDS -> 2 blocks/CU resident.
// Wave w: d-slice [16w,16w+16) (uniform weight rows); lane&31 = t, lane>>5 = K-half.
__global__ __launch_bounds__(512, 4) void proj_kernel(
    const float* __restrict__ feat, const float* __restrict__ w_t,
    float* __restrict__ projn) {
  __shared__ float fs[32 * FSTR];   // 33.3 KB feat tile [t][n]
  __shared__ float ss[8 * 32];
  int b = blockIdx.x >> 7;
  int t0 = (blockIdx.x & 127) << 5;
  int tid = threadIdx.x;

  const float* fb = feat + ((size_t)b * NN) * TT + t0;
  for (int i = tid; i < NN * 32; i += 512) {
    int n = i >> 5, u = i & 31;
    fs[u * FSTR + n] = fb[(size_t)n * TT + u];   // coalesced read, transposed store
  }
  __syncthreads();

  int w = tid >> 6, lane = tid & 63;
  int t = lane & 31, h = lane >> 5;
  int d0 = __builtin_amdgcn_readfirstlane((tid >> 6) * 16);
  float acc[16];
#pragma unroll
  for (int k = 0; k < 16; ++k) acc[k] = 0.f;

  const float* fsr = fs + t * FSTR + h * 128;    // K-half h: n in [128h, 128h+128)
  for (int c = 0; c < 32; ++c) {
    float4 f4 = *(const float4*)(fsr + 4 * c);   // ds_read_b128, 4 n's
    const float* wrow = w_t + (h * 128 + 4 * c) * DD + d0;  // uniform -> scalar loads
#pragma unroll
    for (int q = 0; q < 4; ++q) {
      float fq = (q == 0) ? f4.x : (q == 1) ? f4.y : (q == 2) ? f4.z : f4.w;
      const float4* wv4 = (const float4*)(wrow + q * DD);
#pragma unroll
      for (int k = 0; k < 4; ++k) {
        float4 wv = wv4[k];
        acc[4 * k + 0] += wv.x * fq;
        acc[4 * k + 1] += wv.y * fq;
        acc[4 * k + 2] += wv.z * fq;
        acc[4 * k + 3] += wv.w * fq;
      }
    }
  }
#pragma unroll
  for (int k = 0; k < 16; ++k) acc[k] += __shfl_xor(acc[k], 32, 64);  // K-combine

  float s2 = 0.f;
#pragma unroll
  for (int k = 0; k < 16; ++k) s2 += acc[k] * acc[k];
  if (h == 0) ss[w * 32 + t] = s2;
  __syncthreads();
  float tot = 0.f;
#pragma unroll
  for (int q = 0; q < 8; ++q) tot += ss[q * 32 + t];
  float inv = 1.0f / fmaxf(sqrtf(tot), 1e-12f);

  float4* po = (float4*)(projn + ((size_t)(b * TT + t0 + t)) * DD + d0 + h * 8);
#pragma unroll
  for (int k = 0; k < 2; ++k) {
    int kb = h * 8 + k * 4;
    float4 o;
    o.x = acc[kb + 0] * inv;
    o.y = acc[kb + 1] * inv;
    o.z = acc[kb + 2] * inv;
    o.w = acc[kb + 3] * inv;
    po[k] = o;
  }
}

// ---------------- kernel 3: banded cosine sims + FC + ReLU ----------------
// 256 blocks (XCD-swizzled for halo L2 reuse) x 512 thr. Phase 1: own row in
// 128 VGPRs, scan s (21/wave), other row = wave-uniform LDS broadcast, 4 chains.
__global__ __launch_bounds__(512, 1) void band_fc_kernel(
    const float* __restrict__ projn, const float* __restrict__ wfc_t,
    const float* __restrict__ b_fc, float* __restrict__ out) {
  extern __shared__ float4 smemC[];
  float4* p4 = smemC;                            // [ROWS][RSTR]
  float* band = (float*)(smemC + ROWS * RSTR);   // [64][101]
  // bijective XCD swizzle (nwg=256, 256%8==0): XCD k owns 32 contiguous tiles
  int bid = (blockIdx.x & 7) * 32 + (blockIdx.x >> 3);
  int b = bid >> 6;
  int t0 = (bid & 63) << 6;
  int tid = threadIdx.x;

  const float4* pg = (const float4*)projn;
  for (int i = tid; i < ROWS * 32; i += 512) {
    int r = i >> 5, c = i & 31;
    int t = t0 + r - PADK;
    float4 v = make_float4(0.f, 0.f, 0.f, 0.f);
    if (t >= 0 && t < TT) v = pg[(((size_t)b * TT + t) << 5) + c];
    p4[r * RSTR + c] = v;
  }
  __syncthreads();

  int w = tid >> 6, tt = tid & 63;

  float4 own[32];
#pragma unroll
  for (int c = 0; c < 32; ++c) own[c] = p4[(tt + PADK) * RSTR + c];

  int s0 = w * 21;
  int sEnd = (s0 + 21 < ROWS) ? (s0 + 21) : ROWS;
  for (int s = s0; s < sEnd; ++s) {
    float a0 = 0.f, a1 = 0.f, a2 = 0.f, a3 = 0.f;  // 4 independent chains
#pragma unroll
    for (int c = 0; c < 32; ++c) {
      float4 ov = p4[s * RSTR + c];   // wave-uniform -> LDS broadcast
      a0 += own[c].x * ov.x;
      a1 += own[c].y * ov.y;
      a2 += own[c].z * ov.z;
      a3 += own[c].w * ov.w;
    }
    int j = s - tt;
    if (j >= 0 && j < LK) band[tt * LK + j] = (a0 + a1) + (a2 + a3);
  }
  __syncthreads();

  int o0u = __builtin_amdgcn_readfirstlane((tid >> 6) * 16);
  float acc[16];
  const float4* bf4 = (const float4*)(b_fc + o0u);
#pragma unroll
  for (int k = 0; k < 4; ++k) {
    float4 bv = bf4[k];
    acc[4 * k + 0] = bv.x; acc[4 * k + 1] = bv.y;
    acc[4 * k + 2] = bv.z; acc[4 * k + 3] = bv.w;
  }
#pragma unroll 2
  for (int j = 0; j < LK; ++j) {
    float bv = band[tt * LK + j];                 // gcd(101,32)=1: conflict-free
    const float4* wr = (const float4*)(wfc_t + j * OD + o0u);  // uniform
#pragma unroll
    for (int k = 0; k < 4; ++k) {
      float4 wv = wr[k];
      acc[4 * k + 0] += wv.x * bv;
      acc[4 * k + 1] += wv.y * bv;
      acc[4 * k + 2] += wv.z * bv;
      acc[4 * k + 3] += wv.w * bv;
    }
  }
  float4* og = (float4*)(out + ((size_t)(b * TT + t0 + tt)) * OD + o0u);
#pragma unroll
  for (int k = 0; k < 4; ++k) {
    float4 o;
    o.x = fmaxf(acc[4 * k + 0], 0.f);
    o.y = fmaxf(acc[4 * k + 1], 0.f);
    o.z = fmaxf(acc[4 * k + 2], 0.f);
    o.w = fmaxf(acc[4 * k + 3], 0.f);
    og[k] = o;
  }
}

extern "C" void kernel_launch(void* const* d_in, const int* in_sizes, int n_in,
                              void* d_out, int out_size, void* d_ws, size_t ws_size,
                              hipStream_t stream) {
  const float* x      = (const float*)d_in[0];
  const float* w_proj = (const float*)d_in[1];
  const float* w_fc   = (const float*)d_in[2];
  const float* b_fc   = (const float*)d_in[3];
  float* out = (float*)d_out;

  char* ws = (char*)d_ws;
  float* feat  = (float*)ws;                                    // B*N*T f32  = 16,777,216 B
  float* projn = (float*)(ws + 16777216);                       // B*T*D f32  =  8,388,608 B
  float* w_t   = (float*)(ws + 16777216 + 8388608);             // N*D f32    =    131,072 B
  float* wfc_t = (float*)(ws + 16777216 + 8388608 + 131072);    // LK*OD f32  =     51,712 B

  size_t smC = (size_t)ROWS * RSTR * sizeof(float4) + (size_t)64 * LK * sizeof(float); // 112,448 B
  (void)hipFuncSetAttribute((const void*)band_fc_kernel,
                      hipFuncAttributeMaxDynamicSharedMemorySize, (int)smC);

  pool_kernel<<<(BB * NN * TT) / (64 * CPB), 256, 0, stream>>>(x, feat, w_proj, w_fc, w_t, wfc_t);
  proj_kernel<<<BB * (TT / 32), 512, 0, stream>>>(feat, w_t, projn);
  band_fc_kernel<<<BB * (TT / 64), 512, smC, stream>>>(projn, wfc_t, b_fc, out);
}